// Round 6
// baseline (315.513 us; speedup 1.0000x reference)
//
#include <hip/hip_runtime.h>
#include <hip/hip_cooperative_groups.h>
#include <math.h>

namespace cg = cooperative_groups;

typedef unsigned short u16;
typedef unsigned int   u32;
typedef __attribute__((ext_vector_type(8))) short short8;
typedef __attribute__((ext_vector_type(4))) short s16x4;
typedef __attribute__((ext_vector_type(4))) float f32x4;

// ws layout (float offsets). ws_size = 256 MiB.
#define OFS_XB   0ul          // 32768 x 512 bf16: [pixel][ch]; ch 0-255 = x, 256-511 = agg
#define OFS_W1B  8388608ul    // 256x256 bf16 folded embed weights [o][k]
#define OFS_W2B  8421376ul    // 256x512 bf16 folded enhance weights [o][k]
#define OFS_B1   8486912ul    // 256 fp32
#define OFS_B2   8487168ul    // 256 fp32
#define OFS_POOL 8487424ul    // 8*512 fp32 (atomic-accumulated means)
// fe lives in d_out as [b][px][256ch] bf16 (written transposed by gemm1); enh never materialized

__device__ __forceinline__ u16 f2bf(float x) {
    union { float f; u32 u; } v; v.f = x;
    u32 r = v.u + 0x7fffu + ((v.u >> 16) & 1u);
    return (u16)(r >> 16);
}
__device__ __forceinline__ float bf2f(u16 h) {
    union { u32 u; float f; } v; v.u = ((u32)h) << 16;
    return v.f;
}
__device__ __forceinline__ void ld_g2l_16(u16* l, const u16* g) {
    __builtin_amdgcn_global_load_lds(
        (const __attribute__((address_space(1))) u32*)g,
        (__attribute__((address_space(3))) u32*)l,
        16, 0, 0);
}

// ---------------- cvt (+fused prep): pool zero FIRST, then weights, then x->xb ----------------
__global__ __launch_bounds__(256) void k_cvt(
    const float* __restrict__ x, u16* __restrict__ xb, float* __restrict__ pool,
    const float* __restrict__ w1, const float* __restrict__ b1,
    const float* __restrict__ g1, const float* __restrict__ be1,
    const float* __restrict__ m1, const float* __restrict__ v1,
    const float* __restrict__ w2, const float* __restrict__ b2,
    const float* __restrict__ g2, const float* __restrict__ be2,
    const float* __restrict__ m2, const float* __restrict__ v2,
    u16* __restrict__ w1b, u16* __restrict__ w2b,
    float* __restrict__ b1f, float* __restrict__ b2f)
{
    __shared__ float tile[64][65];
    const int t = threadIdx.x;
    const int id = blockIdx.x;
    if (id < 1) {
        const float4 z = {0.f, 0.f, 0.f, 0.f};
#pragma unroll
        for (int i = 0; i < 4; ++i) ((float4*)pool)[i * 256 + t] = z;
        return;
    }
    if (id < 771) {
        int idx = (id - 1) * 256 + t;
        if (idx < 65536) {
            int o = idx >> 8;
            float inv = g1[o] * rsqrtf(v1[o] + 1e-5f);
            w1b[idx] = f2bf(w1[idx] * inv);
        } else if (idx < 196608) {
            int j = idx - 65536;
            int o = j >> 9;
            float inv = g2[o] * rsqrtf(v2[o] + 1e-5f);
            w2b[j] = f2bf(w2[j] * inv);
        } else if (idx < 196864) {
            int o = idx - 196608;
            float inv = g1[o] * rsqrtf(v1[o] + 1e-5f);
            b1f[o] = b1[o] * inv + be1[o] - m1[o] * inv;
        } else if (idx < 197120) {
            int o = idx - 196864;
            float inv = g2[o] * rsqrtf(v2[o] + 1e-5f);
            b2f[o] = b2[o] * inv + be2[o] - m2[o] * inv;
        }
        return;
    }
    const int cid = id - 771;                // 0..2047
    const int pt = cid & 63, ct = (cid >> 6) & 3, b = cid >> 8;
    const float* src = x + (((size_t)(b * 256 + ct * 64)) << 12) + pt * 64;
#pragma unroll
    for (int i = 0; i < 16; ++i) {
        int idx = i * 256 + t;
        int cl = idx >> 6, pl = idx & 63;
        tile[cl][pl] = src[((size_t)cl << 12) + pl];
    }
    __syncthreads();
#pragma unroll
    for (int i = 0; i < 8; ++i) {
        int idx = i * 256 + t;
        int pl = idx >> 5, c2 = idx & 31;
        int cl = c2 * 2;
        u32 lo = f2bf(tile[cl][pl]);
        u32 hi = f2bf(tile[cl + 1][pl]);
        *(u32*)(xb + (((size_t)(b * 4096 + pt * 64 + pl)) << 9) + ct * 64 + cl) = lo | (hi << 16);
    }
    if (t < 64) {
        float s = 0.f;
#pragma unroll
        for (int i = 0; i < 64; ++i) s += tile[t][i];
        atomicAdd(&pool[(b << 9) + ct * 64 + t], s * (1.f / 4096.f));
    }
}

// ---------------- gemm1: fe = relu(W1 @ x + b1), transposed [px][ch] output ----------------
// 2-phase double-buffered staging: STAGE(next) before compute(cur), 1 barrier/K-tile.
__global__ __launch_bounds__(256) void k_gemm1(
    const u16* __restrict__ xb, const u16* __restrict__ Wb,
    const float* __restrict__ biasf, u16* __restrict__ feT)
{
    constexpr int KIN = 256;
    __shared__ __align__(16) u16 Wl[2][4096];
    __shared__ __align__(16) u16 Xl[2][4096];
    __shared__ __align__(16) u16 ct[16384];
    __shared__ float sbias[128];
    const int t = threadIdx.x;
    const int lane = t & 63;
    const int wv = t >> 6;
    const int id = blockIdx.x;
    const int p_blk = (((id >> 4) << 3) | (id & 7)) * 128;
    const int o_blk = ((id >> 3) & 1) * 128;
    const int owg = (wv & 1) * 4;
    const int pwg = (wv >> 1) * 4;
    const int r16 = lane & 15, q = lane >> 4;
    if (t < 128) sbias[t] = biasf[o_blk + t];

    constexpr int NT = KIN / 32;
    auto STAGE = [&](int buf, int kc) {
        const int kk = kc * 32 + q * 8;
#pragma unroll
        for (int s = 0; s < 4; ++s) {
            const int bi = wv * 4 + s;
            const u16* g;
            u16* l;
            if (bi < 8) {
                g = Wb + (size_t)(o_blk + bi * 16 + r16) * KIN + kk;
                l = Wl[buf] + bi * 512;
            } else {
                g = xb + (((size_t)(p_blk + (bi - 8) * 16 + r16)) << 9) + kk;
                l = Xl[buf] + (bi - 8) * 512;
            }
            ld_g2l_16(l, g);
        }
    };

    f32x4 acc[4][4];
#pragma unroll
    for (int i = 0; i < 4; ++i)
#pragma unroll
        for (int j = 0; j < 4; ++j) acc[i][j] = (f32x4){0.f, 0.f, 0.f, 0.f};

    STAGE(0, 0);
    __syncthreads();
    for (int kc = 0; kc < NT; ++kc) {
        const int cur = kc & 1;
        if (kc + 1 < NT) STAGE(cur ^ 1, kc + 1);
        short8 af[4], bf[4];
#pragma unroll
        for (int i = 0; i < 4; ++i) af[i] = *(const short8*)(Wl[cur] + (owg + i) * 512 + lane * 8);
#pragma unroll
        for (int j = 0; j < 4; ++j) bf[j] = *(const short8*)(Xl[cur] + (pwg + j) * 512 + lane * 8);
#pragma unroll
        for (int i = 0; i < 4; ++i)
#pragma unroll
            for (int j = 0; j < 4; ++j)
                acc[i][j] = __builtin_amdgcn_mfma_f32_16x16x32_bf16(af[i], bf[j], acc[i][j], 0, 0, 0);
        __syncthreads();
    }

    float bia[4][4];
#pragma unroll
    for (int i = 0; i < 4; ++i)
#pragma unroll
        for (int r = 0; r < 4; ++r) bia[i][r] = sbias[owg * 16 + i * 16 + q * 4 + r];
    const int bidx = p_blk >> 12;

    // transpose epilogue: acc -> ct[px][ch] (XOR-swizzled), then coalesced store
#pragma unroll
    for (int i = 0; i < 4; ++i) {
#pragma unroll
        for (int j = 0; j < 4; ++j) {
            const int px_l = pwg * 16 + j * 16 + r16;
#pragma unroll
            for (int rp = 0; rp < 2; ++rp) {
                const int r0 = rp * 2;
                const int o_l = owg * 16 + i * 16 + q * 4 + r0;
                const float v0 = fmaxf(acc[i][j][r0] + bia[i][r0], 0.f);
                const float v1 = fmaxf(acc[i][j][r0 + 1] + bia[i][r0 + 1], 0.f);
                const u32 pk = (u32)f2bf(v0) | ((u32)f2bf(v1) << 16);
                *(u32*)((char*)ct + px_l * 256 + ((o_l * 2) ^ ((px_l & 7) << 4))) = pk;
            }
        }
    }
    __syncthreads();
#pragma unroll
    for (int it = 0; it < 16; ++it) {
        const int idx = it * 256 + t;
        const int px_l = idx >> 5, cd = idx & 31;
        s16x4 v = *(const s16x4*)((char*)ct + px_l * 256 + ((cd * 8) ^ ((px_l & 7) << 4)));
        *(s16x4*)(feT + (((size_t)(bidx * 4096 + (p_blk & 4095) + px_l)) << 8) + o_blk + cd * 4) = v;
    }
}

// ---------------- fused sim + softmax + aggregation (NO LDS STAGING) ----------------
// Direct global reads (L1/L2 serve the 3-row window); independent loads for MLP-level
// parallelism (R5 sliding window regressed: latency-bound => maximize indep loads).
__global__ __launch_bounds__(512) void k_simagg(
    const u16* __restrict__ fe, const u16* __restrict__ xb, u16* __restrict__ xbo)
{
    __shared__ float red[8][64][13];
    __shared__ float ws9[9][64];
    const int t = threadIdx.x;
    const int id = blockIdx.x;
    const int b = id & 7, h = id >> 3;
    const int rows[3] = {h > 0 ? h - 1 : 0, h, h < 63 ? h + 1 : 63};
    const int w = t & 63, sl = t >> 6;

    {
        const int wl = w > 0 ? w - 1 : 0, wr = w < 63 ? w + 1 : 63;
        const int pxs[3] = {wl, w, wr};
        const u16* feb = fe + (((size_t)(b * 4096)) << 8) + sl * 32;
        float cvec[32];
        float dot[9];
        float nn0 = 0.f, nn2 = 0.f;
        {   // center (r=1, j=1)
            const u16* p = feb + (((size_t)(rows[1] * 64 + w)) << 8);
            float s = 0.f;
#pragma unroll
            for (int i = 0; i < 4; ++i) {
                short8 v = *(const short8*)(p + i * 8);
#pragma unroll
                for (int u = 0; u < 8; ++u) {
                    float f = bf2f((u16)v[u]);
                    cvec[i * 8 + u] = f;
                    s = fmaf(f, f, s);
                }
            }
            dot[4] = s;
        }
#pragma unroll
        for (int r = 0; r < 3; ++r) {
#pragma unroll
            for (int j = 0; j < 3; ++j) {
                if (r == 1 && j == 1) continue;
                const int k = r * 3 + j;
                const u16* p = feb + (((size_t)(rows[r] * 64 + pxs[j])) << 8);
                float s = 0.f, qq = 0.f;
#pragma unroll
                for (int i = 0; i < 4; ++i) {
                    short8 v = *(const short8*)(p + i * 8);
#pragma unroll
                    for (int u = 0; u < 8; ++u) {
                        float f = bf2f((u16)v[u]);
                        s = fmaf(cvec[i * 8 + u], f, s);
                        if (j == 1) qq = fmaf(f, f, qq);
                    }
                }
                dot[k] = s;
                if (j == 1) { if (r == 0) nn0 = qq; else nn2 = qq; }
            }
        }
#pragma unroll
        for (int k = 0; k < 9; ++k) red[sl][w][k] = dot[k];
        red[sl][w][9] = nn0;
        red[sl][w][10] = nn2;
    }
    __syncthreads();
    if (t < 64) {
        float dk[9];
#pragma unroll
        for (int k = 0; k < 9; ++k) {
            float s = red[0][w][k];
#pragma unroll
            for (int g = 1; g < 8; ++g) s += red[g][w][k];
            dk[k] = s;
        }
        float nr0 = red[0][w][9], nr2 = red[0][w][10];
#pragma unroll
        for (int g = 1; g < 8; ++g) { nr0 += red[g][w][9]; nr2 += red[g][w][10]; }
        float nr[3] = {nr0, dk[4], nr2};
        const float nc = sqrtf(dk[4]);
        float sv[9], mk[9];
#pragma unroll
        for (int di = -1; di <= 1; ++di) {
#pragma unroll
            for (int dj = -1; dj <= 1; ++dj) {
                const int k = (di + 1) * 3 + (dj + 1);
                const int hn = h + di, wn = w + dj;
                const float mask = (hn >= 0 && hn < 64 && wn >= 0 && wn < 64) ? 1.f : 0.f;
                const int wc = wn < 0 ? 0 : (wn > 63 ? 63 : wn);
                const float nk = __shfl(nr[di + 1], wc, 64);
                mk[k] = mask;
                sv[k] = mask * dk[k] / (nc * sqrtf(nk) + 1e-7f);
            }
        }
        float mx = sv[0];
#pragma unroll
        for (int k = 1; k < 9; ++k) mx = fmaxf(mx, sv[k]);
        float e[9], sum = 0.f;
#pragma unroll
        for (int k = 0; k < 9; ++k) { e[k] = expf(sv[k] - mx); sum += e[k]; }
        const float rs = 1.f / sum;
#pragma unroll
        for (int k = 0; k < 9; ++k) ws9[k][w] = mk[k] * e[k] * rs;
    }
    __syncthreads();
    // aggregation: 9 independent loads per px (R4 form)
    const int cd = t & 63, pxg = t >> 6;
    const u16* xbb = xb + (((size_t)(b * 4096)) << 9) + cd * 4;
    u16* orow = xbo + (((size_t)(b * 4096 + h * 64)) << 9) + 256 + cd * 4;
#pragma unroll
    for (int pi = 0; pi < 8; ++pi) {
        const int px = pxg * 8 + pi;
        const int pL = px > 0 ? px - 1 : 0, pR = px < 63 ? px + 1 : 63;
        const int pxs2[3] = {pL, px, pR};
        float m9[9];
#pragma unroll
        for (int k = 0; k < 9; ++k) m9[k] = ws9[k][px];
        float a0 = 0.f, a1 = 0.f, a2 = 0.f, a3 = 0.f;
#pragma unroll
        for (int r = 0; r < 3; ++r) {
#pragma unroll
            for (int j = 0; j < 3; ++j) {
                const float m = m9[r * 3 + j];
                s16x4 v = *(const s16x4*)(xbb + (((size_t)(rows[r] * 64 + pxs2[j])) << 9));
                a0 = fmaf(bf2f((u16)v[0]), m, a0);
                a1 = fmaf(bf2f((u16)v[1]), m, a1);
                a2 = fmaf(bf2f((u16)v[2]), m, a2);
                a3 = fmaf(bf2f((u16)v[3]), m, a3);
            }
        }
        s16x4 sv4;
        sv4[0] = (short)f2bf(a0); sv4[1] = (short)f2bf(a1);
        sv4[2] = (short)f2bf(a2); sv4[3] = (short)f2bf(a3);
        *(s16x4*)(orow + ((size_t)px << 9)) = sv4;
    }
}

// ---------------- COOPERATIVE gemm2 + gate MLP + final residual ----------------
// Phase 1: enh tile = relu(W2 @ [x;agg] + b2) in acc registers; pool atomics.
// grid.sync(). Phase 2: per-block gate MLP from pool; out = x + gate*enh from regs.
// enh is NEVER written to memory (saves 67 MB round-trip + a dispatch).
__global__ __launch_bounds__(256, 2) void k_gemm2f(
    const u16* __restrict__ xb, const u16* __restrict__ Wb,
    const float* __restrict__ biasf, const float* __restrict__ x,
    const float* __restrict__ wg1, const float* __restrict__ bg1,
    const float* __restrict__ wg2, const float* __restrict__ bg2,
    float* __restrict__ pool, float* __restrict__ out)
{
    constexpr int KIN = 512;
    __shared__ __align__(16) u16 Wl[2][4096];
    __shared__ __align__(16) u16 Xl[2][4096];
    __shared__ float sbias[128];
    __shared__ float pl[512];
    __shared__ float hpart[4][64];
    __shared__ float hb[64];
    __shared__ float sg[256];
    const int t = threadIdx.x;
    const int lane = t & 63;
    const int wv = t >> 6;
    const int id = blockIdx.x;
    const int p_blk = (((id >> 4) << 3) | (id & 7)) * 128;
    const int o_blk = ((id >> 3) & 1) * 128;
    const int owg = (wv & 1) * 4;
    const int pwg = (wv >> 1) * 4;
    const int r16 = lane & 15, q = lane >> 4;
    if (t < 128) sbias[t] = biasf[o_blk + t];

    constexpr int NT = KIN / 32;
    auto STAGE = [&](int buf, int kc) {
        const int kk = kc * 32 + q * 8;
#pragma unroll
        for (int s = 0; s < 4; ++s) {
            const int bi = wv * 4 + s;
            const u16* g;
            u16* l;
            if (bi < 8) {
                g = Wb + (size_t)(o_blk + bi * 16 + r16) * KIN + kk;
                l = Wl[buf] + bi * 512;
            } else {
                g = xb + (((size_t)(p_blk + (bi - 8) * 16 + r16)) << 9) + kk;
                l = Xl[buf] + (bi - 8) * 512;
            }
            ld_g2l_16(l, g);
        }
    };

    f32x4 acc[4][4];
#pragma unroll
    for (int i = 0; i < 4; ++i)
#pragma unroll
        for (int j = 0; j < 4; ++j) acc[i][j] = (f32x4){0.f, 0.f, 0.f, 0.f};

    STAGE(0, 0);
    __syncthreads();
    for (int kc = 0; kc < NT; ++kc) {
        const int cur = kc & 1;
        if (kc + 1 < NT) STAGE(cur ^ 1, kc + 1);
        short8 af[4], bf[4];
#pragma unroll
        for (int i = 0; i < 4; ++i) af[i] = *(const short8*)(Wl[cur] + (owg + i) * 512 + lane * 8);
#pragma unroll
        for (int j = 0; j < 4; ++j) bf[j] = *(const short8*)(Xl[cur] + (pwg + j) * 512 + lane * 8);
#pragma unroll
        for (int i = 0; i < 4; ++i)
#pragma unroll
            for (int j = 0; j < 4; ++j)
                acc[i][j] = __builtin_amdgcn_mfma_f32_16x16x32_bf16(af[i], bf[j], acc[i][j], 0, 0, 0);
        __syncthreads();
    }

    float bia[4][4];
#pragma unroll
    for (int i = 0; i < 4; ++i)
#pragma unroll
        for (int r = 0; r < 4; ++r) bia[i][r] = sbias[owg * 16 + i * 16 + q * 4 + r];
    const int bidx = p_blk >> 12;

    // ---- fused pool (pre-sync): mean over pixels of relu(enh)
#pragma unroll
    for (int i = 0; i < 4; ++i) {
#pragma unroll
        for (int r = 0; r < 4; ++r) {
            const int o = o_blk + owg * 16 + i * 16 + q * 4 + r;
            float ps = 0.f;
#pragma unroll
            for (int j = 0; j < 4; ++j)
                ps += fmaxf(acc[i][j][r] + bia[i][r], 0.f);
            ps += __shfl_down(ps, 8, 16);
            ps += __shfl_down(ps, 4, 16);
            ps += __shfl_down(ps, 2, 16);
            ps += __shfl_down(ps, 1, 16);
            if (r16 == 0)
                atomicAdd(&pool[(bidx << 9) + 256 + o], ps * (1.f / 4096.f));
        }
    }
    __threadfence();
    cg::this_grid().sync();

    // ---- gate MLP (per-block recompute; weights are L2-resident)
    pl[t] = pool[bidx * 512 + t];
    pl[t + 256] = pool[bidx * 512 + 256 + t];
    __syncthreads();
    {
        const int o = t & 63, seg = t >> 6;
        float s = 0.f;
        const float* wr_ = wg1 + o * 512 + seg * 128;
        const float* pr_ = pl + seg * 128;
#pragma unroll 4
        for (int j = 0; j < 128; ++j) s = fmaf(wr_[j], pr_[j], s);
        hpart[seg][o] = s;
    }
    __syncthreads();
    if (t < 64)
        hb[t] = fmaxf(hpart[0][t] + hpart[1][t] + hpart[2][t] + hpart[3][t] + bg1[t], 0.f);
    __syncthreads();
    {
        float s2 = bg2[t];
        const float* w2 = wg2 + t * 64;
#pragma unroll 4
        for (int j = 0; j < 64; ++j) s2 = fmaf(w2[j], hb[j], s2);
        sg[t] = 1.f / (1.f + expf(-s2));
    }
    __syncthreads();

    // ---- epilogue: out = x + gate * enh (from registers; coalesced 16-px runs)
    const int pin0 = (p_blk & 4095) + pwg * 16 + r16;
#pragma unroll
    for (int i = 0; i < 4; ++i) {
#pragma unroll
        for (int r = 0; r < 4; ++r) {
            const int o = o_blk + owg * 16 + i * 16 + q * 4 + r;
            const float gt = sg[o];
            const size_t rowb = ((size_t)(bidx * 256 + o)) << 12;
#pragma unroll
            for (int j = 0; j < 4; ++j) {
                const float v = fmaxf(acc[i][j][r] + bia[i][r], 0.f);
                const size_t off = rowb + pin0 + j * 16;
                out[off] = fmaf(gt, v, x[off]);
            }
        }
    }
}

extern "C" void kernel_launch(void* const* d_in, const int* in_sizes, int n_in,
                              void* d_out, int out_size, void* d_ws, size_t ws_size,
                              hipStream_t stream)
{
    const float* x       = (const float*)d_in[0];
    const float* w_embed = (const float*)d_in[1];
    const float* b_embed = (const float*)d_in[2];
    const float* g1      = (const float*)d_in[3];
    const float* be1     = (const float*)d_in[4];
    const float* m1      = (const float*)d_in[5];
    const float* v1      = (const float*)d_in[6];
    const float* w_enh   = (const float*)d_in[7];
    const float* b_enh   = (const float*)d_in[8];
    const float* g2      = (const float*)d_in[9];
    const float* be2     = (const float*)d_in[10];
    const float* m2      = (const float*)d_in[11];
    const float* v2      = (const float*)d_in[12];
    const float* w_g1    = (const float*)d_in[13];
    const float* b_g1    = (const float*)d_in[14];
    const float* w_g2    = (const float*)d_in[15];
    const float* b_g2    = (const float*)d_in[16];
    float* ws  = (float*)d_ws;
    float* out = (float*)d_out;

    u16*   xb   = (u16*)(ws + OFS_XB);
    u16*   w1b  = (u16*)(ws + OFS_W1B);
    u16*   w2b  = (u16*)(ws + OFS_W2B);
    float* b1f  = ws + OFS_B1;
    float* b2f  = ws + OFS_B2;
    float* pool = ws + OFS_POOL;
    u16*   fe   = (u16*)d_out;   // fe (bf16 [b][px][ch]) in d_out; dead before k_gemm2f writes out

    k_cvt<<<dim3(2819), dim3(256), 0, stream>>>(
        x, xb, pool,
        w_embed, b_embed, g1, be1, m1, v1,
        w_enh, b_enh, g2, be2, m2, v2, w1b, w2b, b1f, b2f);
    k_gemm1<<<dim3(512), dim3(256), 0, stream>>>(xb, w1b, b1f, fe);
    k_simagg<<<dim3(512), dim3(512), 0, stream>>>(fe, xb, xb);
    {
        void* args[] = {(void*)&xb, (void*)&w2b, (void*)&b2f, (void*)&x,
                        (void*)&w_g1, (void*)&b_g1, (void*)&w_g2, (void*)&b_g2,
                        (void*)&pool, (void*)&out};
        hipLaunchCooperativeKernel((const void*)k_gemm2f, dim3(512), dim3(256),
                                   args, 0, stream);
    }
}

// Round 7
// 211.916 us; speedup vs baseline: 1.4889x; 1.4889x over previous
//
#include <hip/hip_runtime.h>
#include <math.h>

typedef unsigned short u16;
typedef unsigned int   u32;
typedef __attribute__((ext_vector_type(8))) short short8;
typedef __attribute__((ext_vector_type(4))) short s16x4;
typedef __attribute__((ext_vector_type(4))) float f32x4;

// ws layout (float offsets). ws_size = 256 MiB.
#define OFS_XB   0ul          // 32768 x 512 bf16: [pixel][ch]; ch 0-255 = x, 256-511 = agg
#define OFS_W1B  8388608ul    // 256x256 bf16 folded embed weights [o][k]
#define OFS_W2B  8421376ul    // 256x512 bf16 folded enhance weights [o][k]
#define OFS_B1   8486912ul    // 256 fp32
#define OFS_B2   8487168ul    // 256 fp32
#define OFS_POOL 8487424ul    // 8*512 fp32 (atomic-accumulated means)
#define OFS_ENH  8491520ul    // 8x256x4096 bf16 enhanced [b][c][px]
#define OFS_XC   16880128ul   // 8x256x4096 bf16 x copy [b][c][px] (k_final residual)
// fe lives in d_out as [b][px][256ch] bf16 (written transposed by gemm1)

__device__ __forceinline__ u16 f2bf(float x) {
    union { float f; u32 u; } v; v.f = x;
    u32 r = v.u + 0x7fffu + ((v.u >> 16) & 1u);
    return (u16)(r >> 16);
}
__device__ __forceinline__ float bf2f(u16 h) {
    union { u32 u; float f; } v; v.u = ((u32)h) << 16;
    return v.f;
}
__device__ __forceinline__ void ld_g2l_16(u16* l, const u16* g) {
    __builtin_amdgcn_global_load_lds(
        (const __attribute__((address_space(1))) u32*)g,
        (__attribute__((address_space(3))) u32*)l,
        16, 0, 0);
}

// ---------------- cvt (+fused prep): pool zero FIRST, then weights, then x->xb,xc ----------------
__global__ __launch_bounds__(256) void k_cvt(
    const float* __restrict__ x, u16* __restrict__ xb, u16* __restrict__ xc,
    float* __restrict__ pool,
    const float* __restrict__ w1, const float* __restrict__ b1,
    const float* __restrict__ g1, const float* __restrict__ be1,
    const float* __restrict__ m1, const float* __restrict__ v1,
    const float* __restrict__ w2, const float* __restrict__ b2,
    const float* __restrict__ g2, const float* __restrict__ be2,
    const float* __restrict__ m2, const float* __restrict__ v2,
    u16* __restrict__ w1b, u16* __restrict__ w2b,
    float* __restrict__ b1f, float* __restrict__ b2f)
{
    __shared__ float tile[64][65];
    const int t = threadIdx.x;
    const int id = blockIdx.x;
    if (id < 1) {
        const float4 z = {0.f, 0.f, 0.f, 0.f};
#pragma unroll
        for (int i = 0; i < 4; ++i) ((float4*)pool)[i * 256 + t] = z;
        return;
    }
    if (id < 771) {
        int idx = (id - 1) * 256 + t;
        if (idx < 65536) {
            int o = idx >> 8;
            float inv = g1[o] * rsqrtf(v1[o] + 1e-5f);
            w1b[idx] = f2bf(w1[idx] * inv);
        } else if (idx < 196608) {
            int j = idx - 65536;
            int o = j >> 9;
            float inv = g2[o] * rsqrtf(v2[o] + 1e-5f);
            w2b[j] = f2bf(w2[j] * inv);
        } else if (idx < 196864) {
            int o = idx - 196608;
            float inv = g1[o] * rsqrtf(v1[o] + 1e-5f);
            b1f[o] = b1[o] * inv + be1[o] - m1[o] * inv;
        } else if (idx < 197120) {
            int o = idx - 196864;
            float inv = g2[o] * rsqrtf(v2[o] + 1e-5f);
            b2f[o] = b2[o] * inv + be2[o] - m2[o] * inv;
        }
        return;
    }
    const int cid = id - 771;                // 0..2047
    const int pt = cid & 63, ct = (cid >> 6) & 3, b = cid >> 8;
    const float* src = x + (((size_t)(b * 256 + ct * 64)) << 12) + pt * 64;
#pragma unroll
    for (int i = 0; i < 16; ++i) {
        int idx = i * 256 + t;
        int cl = idx >> 6, pl = idx & 63;
        tile[cl][pl] = src[((size_t)cl << 12) + pl];
    }
    __syncthreads();
#pragma unroll
    for (int i = 0; i < 8; ++i) {            // xb: [px][ch] transposed bf16
        int idx = i * 256 + t;
        int pl = idx >> 5, c2 = idx & 31;
        int cl = c2 * 2;
        u32 lo = f2bf(tile[cl][pl]);
        u32 hi = f2bf(tile[cl + 1][pl]);
        *(u32*)(xb + (((size_t)(b * 4096 + pt * 64 + pl)) << 9) + ct * 64 + cl) = lo | (hi << 16);
    }
#pragma unroll
    for (int i = 0; i < 8; ++i) {            // xc: [c][px] bf16 cast (same layout as x)
        int idx = i * 256 + t;
        int cl = idx >> 5, pl2 = (idx & 31) * 2;
        u32 lo = f2bf(tile[cl][pl2]);
        u32 hi = f2bf(tile[cl][pl2 + 1]);
        *(u32*)(xc + (((size_t)(b * 256 + ct * 64 + cl)) << 12) + pt * 64 + pl2) = lo | (hi << 16);
    }
    if (t < 64) {
        float s = 0.f;
#pragma unroll
        for (int i = 0; i < 64; ++i) s += tile[t][i];
        atomicAdd(&pool[(b << 9) + ct * 64 + t], s * (1.f / 4096.f));
    }
}

// ---------------- bf16 MFMA GEMM: out = relu(W @ X + bias) (single-buffer, R3 form) ----------------
// OUTT=true: write output transposed [px][ch] via 32KB LDS tile. DOPOOL: fused mean-pool.
template<int KIN, bool OUTT, bool DOPOOL>
__global__ __launch_bounds__(256) void k_gemm(
    const u16* __restrict__ xb, const u16* __restrict__ Wb,
    const float* __restrict__ biasf, void* __restrict__ outp,
    float* __restrict__ poolp)
{
    __shared__ __align__(16) u16 Wl[4096];
    __shared__ __align__(16) u16 Xl[4096];
    __shared__ __align__(16) u16 ct[OUTT ? 16384 : 4];
    __shared__ float sbias[128];
    const int t = threadIdx.x;
    const int lane = t & 63;
    const int wv = t >> 6;
    const int id = blockIdx.x;
    const int p_blk = (((id >> 4) << 3) | (id & 7)) * 128;
    const int o_blk = ((id >> 3) & 1) * 128;
    const int owg = (wv & 1) * 4;
    const int pwg = (wv >> 1) * 4;
    const int r16 = lane & 15, q = lane >> 4;
    if (t < 128) sbias[t] = biasf[o_blk + t];

    f32x4 acc[4][4];
#pragma unroll
    for (int i = 0; i < 4; ++i)
#pragma unroll
        for (int j = 0; j < 4; ++j) acc[i][j] = (f32x4){0.f, 0.f, 0.f, 0.f};

    for (int kc = 0; kc < KIN / 32; ++kc) {
        const int kk = kc * 32 + q * 8;
#pragma unroll
        for (int s = 0; s < 4; ++s) {
            const int bi = wv * 4 + s;
            const u16* g;
            u16* l;
            if (bi < 8) {
                g = Wb + (size_t)(o_blk + bi * 16 + r16) * KIN + kk;
                l = Wl + bi * 512;
            } else {
                g = xb + (((size_t)(p_blk + (bi - 8) * 16 + r16)) << 9) + kk;
                l = Xl + (bi - 8) * 512;
            }
            ld_g2l_16(l, g);
        }
        __syncthreads();
        short8 af[4], bf[4];
#pragma unroll
        for (int i = 0; i < 4; ++i) af[i] = *(const short8*)(Wl + (owg + i) * 512 + lane * 8);
#pragma unroll
        for (int j = 0; j < 4; ++j) bf[j] = *(const short8*)(Xl + (pwg + j) * 512 + lane * 8);
#pragma unroll
        for (int i = 0; i < 4; ++i)
#pragma unroll
            for (int j = 0; j < 4; ++j)
                acc[i][j] = __builtin_amdgcn_mfma_f32_16x16x32_bf16(af[i], bf[j], acc[i][j], 0, 0, 0);
        __syncthreads();
    }

    float bia[4][4];
#pragma unroll
    for (int i = 0; i < 4; ++i)
#pragma unroll
        for (int r = 0; r < 4; ++r) bia[i][r] = sbias[owg * 16 + i * 16 + q * 4 + r];
    const int bidx = p_blk >> 12;

    if (OUTT) {
        // transpose epilogue: acc -> ct[px][ch] (XOR-swizzled), then coalesced store
#pragma unroll
        for (int i = 0; i < 4; ++i) {
#pragma unroll
            for (int j = 0; j < 4; ++j) {
                const int px_l = pwg * 16 + j * 16 + r16;
#pragma unroll
                for (int rp = 0; rp < 2; ++rp) {
                    const int r0 = rp * 2;
                    const int o_l = owg * 16 + i * 16 + q * 4 + r0;
                    const float v0 = fmaxf(acc[i][j][r0] + bia[i][r0], 0.f);
                    const float v1 = fmaxf(acc[i][j][r0 + 1] + bia[i][r0 + 1], 0.f);
                    const u32 pk = (u32)f2bf(v0) | ((u32)f2bf(v1) << 16);
                    *(u32*)((char*)ct + px_l * 256 + ((o_l * 2) ^ ((px_l & 7) << 4))) = pk;
                }
            }
        }
        __syncthreads();
        u16* feT = (u16*)outp;
#pragma unroll
        for (int it = 0; it < 16; ++it) {
            const int idx = it * 256 + t;
            const int px_l = idx >> 5, cd = idx & 31;
            s16x4 v = *(const s16x4*)((char*)ct + px_l * 256 + ((cd * 8) ^ ((px_l & 7) << 4)));
            *(s16x4*)(feT + (((size_t)(bidx * 4096 + (p_blk & 4095) + px_l)) << 8) + o_blk + cd * 4) = v;
        }
        return;
    }

    const int pin0 = (p_blk & 4095) + pwg * 16 + r16;
#pragma unroll
    for (int i = 0; i < 4; ++i) {
#pragma unroll
        for (int r = 0; r < 4; ++r) {
            const int o = o_blk + owg * 16 + i * 16 + q * 4 + r;
            const size_t rowb = ((size_t)(bidx * 256 + o)) << 12;
            float ps = 0.f;
#pragma unroll
            for (int j = 0; j < 4; ++j) {
                float v = fmaxf(acc[i][j][r] + bia[i][r], 0.f);
                const size_t oi = rowb + pin0 + j * 16;
                ((u16*)outp)[oi] = f2bf(v);
                ps += v;
            }
            if (DOPOOL) {
                ps += __shfl_down(ps, 8, 16);
                ps += __shfl_down(ps, 4, 16);
                ps += __shfl_down(ps, 2, 16);
                ps += __shfl_down(ps, 1, 16);
                if (r16 == 0)
                    atomicAdd(&poolp[(bidx << 9) + 256 + o], ps * (1.f / 4096.f));
            }
        }
    }
}

// ---------------- fused sim + softmax + aggregation (NO LDS STAGING; R4-proven) ----------------
__global__ __launch_bounds__(512) void k_simagg(
    const u16* __restrict__ fe, const u16* __restrict__ xb, u16* __restrict__ xbo)
{
    __shared__ float red[8][64][13];
    __shared__ float ws9[9][64];
    const int t = threadIdx.x;
    const int id = blockIdx.x;
    const int b = id & 7, h = id >> 3;
    const int rows[3] = {h > 0 ? h - 1 : 0, h, h < 63 ? h + 1 : 63};
    const int w = t & 63, sl = t >> 6;

    {
        const int wl = w > 0 ? w - 1 : 0, wr = w < 63 ? w + 1 : 63;
        const int pxs[3] = {wl, w, wr};
        const u16* feb = fe + (((size_t)(b * 4096)) << 8) + sl * 32;
        float cvec[32];
        float dot[9];
        float nn0 = 0.f, nn2 = 0.f;
        {   // center (r=1, j=1)
            const u16* p = feb + (((size_t)(rows[1] * 64 + w)) << 8);
            float s = 0.f;
#pragma unroll
            for (int i = 0; i < 4; ++i) {
                short8 v = *(const short8*)(p + i * 8);
#pragma unroll
                for (int u = 0; u < 8; ++u) {
                    float f = bf2f((u16)v[u]);
                    cvec[i * 8 + u] = f;
                    s = fmaf(f, f, s);
                }
            }
            dot[4] = s;
        }
#pragma unroll
        for (int r = 0; r < 3; ++r) {
#pragma unroll
            for (int j = 0; j < 3; ++j) {
                if (r == 1 && j == 1) continue;
                const int k = r * 3 + j;
                const u16* p = feb + (((size_t)(rows[r] * 64 + pxs[j])) << 8);
                float s = 0.f, qq = 0.f;
#pragma unroll
                for (int i = 0; i < 4; ++i) {
                    short8 v = *(const short8*)(p + i * 8);
#pragma unroll
                    for (int u = 0; u < 8; ++u) {
                        float f = bf2f((u16)v[u]);
                        s = fmaf(cvec[i * 8 + u], f, s);
                        if (j == 1) qq = fmaf(f, f, qq);
                    }
                }
                dot[k] = s;
                if (j == 1) { if (r == 0) nn0 = qq; else nn2 = qq; }
            }
        }
#pragma unroll
        for (int k = 0; k < 9; ++k) red[sl][w][k] = dot[k];
        red[sl][w][9] = nn0;
        red[sl][w][10] = nn2;
    }
    __syncthreads();
    if (t < 64) {
        float dk[9];
#pragma unroll
        for (int k = 0; k < 9; ++k) {
            float s = red[0][w][k];
#pragma unroll
            for (int g = 1; g < 8; ++g) s += red[g][w][k];
            dk[k] = s;
        }
        float nr0 = red[0][w][9], nr2 = red[0][w][10];
#pragma unroll
        for (int g = 1; g < 8; ++g) { nr0 += red[g][w][9]; nr2 += red[g][w][10]; }
        float nr[3] = {nr0, dk[4], nr2};
        const float nc = sqrtf(dk[4]);
        float sv[9], mk[9];
#pragma unroll
        for (int di = -1; di <= 1; ++di) {
#pragma unroll
            for (int dj = -1; dj <= 1; ++dj) {
                const int k = (di + 1) * 3 + (dj + 1);
                const int hn = h + di, wn = w + dj;
                const float mask = (hn >= 0 && hn < 64 && wn >= 0 && wn < 64) ? 1.f : 0.f;
                const int wc = wn < 0 ? 0 : (wn > 63 ? 63 : wn);
                const float nk = __shfl(nr[di + 1], wc, 64);
                mk[k] = mask;
                sv[k] = mask * dk[k] / (nc * sqrtf(nk) + 1e-7f);
            }
        }
        float mx = sv[0];
#pragma unroll
        for (int k = 1; k < 9; ++k) mx = fmaxf(mx, sv[k]);
        float e[9], sum = 0.f;
#pragma unroll
        for (int k = 0; k < 9; ++k) { e[k] = expf(sv[k] - mx); sum += e[k]; }
        const float rs = 1.f / sum;
#pragma unroll
        for (int k = 0; k < 9; ++k) ws9[k][w] = mk[k] * e[k] * rs;
    }
    __syncthreads();
    // aggregation: 9 independent loads per px
    const int cd = t & 63, pxg = t >> 6;
    const u16* xbb = xb + (((size_t)(b * 4096)) << 9) + cd * 4;
    u16* orow = xbo + (((size_t)(b * 4096 + h * 64)) << 9) + 256 + cd * 4;
#pragma unroll
    for (int pi = 0; pi < 8; ++pi) {
        const int px = pxg * 8 + pi;
        const int pL = px > 0 ? px - 1 : 0, pR = px < 63 ? px + 1 : 63;
        const int pxs2[3] = {pL, px, pR};
        float m9[9];
#pragma unroll
        for (int k = 0; k < 9; ++k) m9[k] = ws9[k][px];
        float a0 = 0.f, a1 = 0.f, a2 = 0.f, a3 = 0.f;
#pragma unroll
        for (int r = 0; r < 3; ++r) {
#pragma unroll
            for (int j = 0; j < 3; ++j) {
                const float m = m9[r * 3 + j];
                s16x4 v = *(const s16x4*)(xbb + (((size_t)(rows[r] * 64 + pxs2[j])) << 9));
                a0 = fmaf(bf2f((u16)v[0]), m, a0);
                a1 = fmaf(bf2f((u16)v[1]), m, a1);
                a2 = fmaf(bf2f((u16)v[2]), m, a2);
                a3 = fmaf(bf2f((u16)v[3]), m, a3);
            }
        }
        s16x4 sv4;
        sv4[0] = (short)f2bf(a0); sv4[1] = (short)f2bf(a1);
        sv4[2] = (short)f2bf(a2); sv4[3] = (short)f2bf(a3);
        *(s16x4*)(orow + ((size_t)px << 9)) = sv4;
    }
}

// ---------------- final: gate MLP (per-block recompute) + residual add ----------------
// Residual from xc (bf16 [c][px], 33.5 MB) instead of fp32 x (134 MB): -100 MB HBM.
__global__ __launch_bounds__(256) void k_final(
    const u16* __restrict__ xc, const u16* __restrict__ enh,
    const float* __restrict__ pool,
    const float* __restrict__ wg1, const float* __restrict__ bg1,
    const float* __restrict__ wg2, const float* __restrict__ bg2,
    float* __restrict__ out)
{
    __shared__ float pl[512];
    __shared__ float hpart[4][64];
    __shared__ float hb[64];
    __shared__ float sg[256];
    const int t = threadIdx.x;
    const int id = blockIdx.x;               // 512 = b(8) x 64 ch-groups
    const int b = id & 7, cg = id >> 3;
    pl[t] = pool[b * 512 + t];
    pl[t + 256] = pool[b * 512 + 256 + t];
    __syncthreads();
    {
        const int o = t & 63, seg = t >> 6;
        float s = 0.f;
        const float* wr_ = wg1 + o * 512 + seg * 128;
        const float* pr_ = pl + seg * 128;
#pragma unroll 4
        for (int j = 0; j < 128; ++j) s = fmaf(wr_[j], pr_[j], s);
        hpart[seg][o] = s;
    }
    __syncthreads();
    if (t < 64)
        hb[t] = fmaxf(hpart[0][t] + hpart[1][t] + hpart[2][t] + hpart[3][t] + bg1[t], 0.f);
    __syncthreads();
    {
        float s2 = bg2[t];
        const float* w2 = wg2 + t * 64;
#pragma unroll 4
        for (int j = 0; j < 64; ++j) s2 = fmaf(w2[j], hb[j], s2);
        sg[t] = 1.f / (1.f + expf(-s2));
    }
    __syncthreads();
    const int cl = t >> 6, l = t & 63;
    const int c = cg * 4 + cl;
    const float gt = sg[c];
    const u16* xp = xc + (((size_t)(b * 256 + c)) << 12);
    const u16* ep = enh + (((size_t)(b * 256 + c)) << 12);
    float*     op = out + (((size_t)(b * 256 + c)) << 12);
#pragma unroll
    for (int ch = 0; ch < 8; ++ch) {         // 8 chunks of 512 px
        const int base = ch * 512 + l * 8;
        short8 ev = *(const short8*)(ep + base);
        short8 xv = *(const short8*)(xp + base);
        float4 o0, o1;
        o0.x = fmaf(gt, bf2f((u16)ev[0]), bf2f((u16)xv[0]));
        o0.y = fmaf(gt, bf2f((u16)ev[1]), bf2f((u16)xv[1]));
        o0.z = fmaf(gt, bf2f((u16)ev[2]), bf2f((u16)xv[2]));
        o0.w = fmaf(gt, bf2f((u16)ev[3]), bf2f((u16)xv[3]));
        o1.x = fmaf(gt, bf2f((u16)ev[4]), bf2f((u16)xv[4]));
        o1.y = fmaf(gt, bf2f((u16)ev[5]), bf2f((u16)xv[5]));
        o1.z = fmaf(gt, bf2f((u16)ev[6]), bf2f((u16)xv[6]));
        o1.w = fmaf(gt, bf2f((u16)ev[7]), bf2f((u16)xv[7]));
        *(float4*)(op + base) = o0;
        *(float4*)(op + base + 4) = o1;
    }
}

extern "C" void kernel_launch(void* const* d_in, const int* in_sizes, int n_in,
                              void* d_out, int out_size, void* d_ws, size_t ws_size,
                              hipStream_t stream)
{
    const float* x       = (const float*)d_in[0];
    const float* w_embed = (const float*)d_in[1];
    const float* b_embed = (const float*)d_in[2];
    const float* g1      = (const float*)d_in[3];
    const float* be1     = (const float*)d_in[4];
    const float* m1      = (const float*)d_in[5];
    const float* v1      = (const float*)d_in[6];
    const float* w_enh   = (const float*)d_in[7];
    const float* b_enh   = (const float*)d_in[8];
    const float* g2      = (const float*)d_in[9];
    const float* be2     = (const float*)d_in[10];
    const float* m2      = (const float*)d_in[11];
    const float* v2      = (const float*)d_in[12];
    const float* w_g1    = (const float*)d_in[13];
    const float* b_g1    = (const float*)d_in[14];
    const float* w_g2    = (const float*)d_in[15];
    const float* b_g2    = (const float*)d_in[16];
    float* ws  = (float*)d_ws;
    float* out = (float*)d_out;

    u16*   xb   = (u16*)(ws + OFS_XB);
    u16*   w1b  = (u16*)(ws + OFS_W1B);
    u16*   w2b  = (u16*)(ws + OFS_W2B);
    float* b1f  = ws + OFS_B1;
    float* b2f  = ws + OFS_B2;
    float* pool = ws + OFS_POOL;
    u16*   enh  = (u16*)(ws + OFS_ENH);
    u16*   xc   = (u16*)(ws + OFS_XC);
    u16*   fe   = (u16*)d_out;   // fe (bf16 [b][px][ch]) in d_out; dead before k_final writes

    k_cvt<<<dim3(2819), dim3(256), 0, stream>>>(
        x, xb, xc, pool,
        w_embed, b_embed, g1, be1, m1, v1,
        w_enh, b_enh, g2, be2, m2, v2, w1b, w2b, b1f, b2f);
    k_gemm<256, true, false><<<dim3(512), dim3(256), 0, stream>>>(xb, w1b, b1f, (void*)fe, nullptr);
    k_simagg<<<dim3(512), dim3(512), 0, stream>>>(fe, xb, xb);
    k_gemm<512, false, true><<<dim3(512), dim3(256), 0, stream>>>(xb, w2b, b2f, (void*)enh, pool);
    k_final<<<dim3(512), dim3(256), 0, stream>>>(xc, enh, pool, w_g1, b_g1, w_g2, b_g2, out);
}

// Round 8
// 199.884 us; speedup vs baseline: 1.5785x; 1.0602x over previous
//
#include <hip/hip_runtime.h>
#include <math.h>

typedef unsigned short u16;
typedef unsigned int   u32;
typedef __attribute__((ext_vector_type(8))) short short8;
typedef __attribute__((ext_vector_type(4))) short s16x4;
typedef __attribute__((ext_vector_type(4))) float f32x4;

// ws layout (float offsets). ws_size = 256 MiB.
#define OFS_XB   0ul          // 32768 x 512 bf16: [pixel][ch]; ch 0-255 = x, 256-511 = agg
#define OFS_W1B  8388608ul    // 256x256 bf16 folded embed weights [o][k]
#define OFS_W2B  8421376ul    // 256x512 bf16 folded enhance weights [o][k]
#define OFS_B1   8486912ul    // 256 fp32
#define OFS_B2   8487168ul    // 256 fp32
#define OFS_POOL 8487424ul    // 8*512 fp32 (atomic-accumulated means)
#define OFS_ENH  8491520ul    // 8x256x4096 bf16 enhanced [b][c][px]
#define OFS_XC   16880128ul   // 8x256x4096 bf16 x copy [b][c][px] (k_final residual)
// fe lives in d_out as [b][px][256ch] bf16 (written transposed by gemm1)

__device__ __forceinline__ u16 f2bf(float x) {
    union { float f; u32 u; } v; v.f = x;
    u32 r = v.u + 0x7fffu + ((v.u >> 16) & 1u);
    return (u16)(r >> 16);
}
__device__ __forceinline__ float bf2f(u16 h) {
    union { u32 u; float f; } v; v.u = ((u32)h) << 16;
    return v.f;
}
__device__ __forceinline__ void ld_g2l_16(u16* l, const u16* g) {
    __builtin_amdgcn_global_load_lds(
        (const __attribute__((address_space(1))) u32*)g,
        (__attribute__((address_space(3))) u32*)l,
        16, 0, 0);
}

// ---------------- cvt (+fused prep): pool zero FIRST, then weights, then x->xb,xc ----------------
__global__ __launch_bounds__(256) void k_cvt(
    const float* __restrict__ x, u16* __restrict__ xb, u16* __restrict__ xc,
    float* __restrict__ pool,
    const float* __restrict__ w1, const float* __restrict__ b1,
    const float* __restrict__ g1, const float* __restrict__ be1,
    const float* __restrict__ m1, const float* __restrict__ v1,
    const float* __restrict__ w2, const float* __restrict__ b2,
    const float* __restrict__ g2, const float* __restrict__ be2,
    const float* __restrict__ m2, const float* __restrict__ v2,
    u16* __restrict__ w1b, u16* __restrict__ w2b,
    float* __restrict__ b1f, float* __restrict__ b2f)
{
    __shared__ float tile[64][65];
    const int t = threadIdx.x;
    const int id = blockIdx.x;
    if (id < 1) {
        const float4 z = {0.f, 0.f, 0.f, 0.f};
#pragma unroll
        for (int i = 0; i < 4; ++i) ((float4*)pool)[i * 256 + t] = z;
        return;
    }
    if (id < 771) {
        int idx = (id - 1) * 256 + t;
        if (idx < 65536) {
            int o = idx >> 8;
            float inv = g1[o] * rsqrtf(v1[o] + 1e-5f);
            w1b[idx] = f2bf(w1[idx] * inv);
        } else if (idx < 196608) {
            int j = idx - 65536;
            int o = j >> 9;
            float inv = g2[o] * rsqrtf(v2[o] + 1e-5f);
            w2b[j] = f2bf(w2[j] * inv);
        } else if (idx < 196864) {
            int o = idx - 196608;
            float inv = g1[o] * rsqrtf(v1[o] + 1e-5f);
            b1f[o] = b1[o] * inv + be1[o] - m1[o] * inv;
        } else if (idx < 197120) {
            int o = idx - 196864;
            float inv = g2[o] * rsqrtf(v2[o] + 1e-5f);
            b2f[o] = b2[o] * inv + be2[o] - m2[o] * inv;
        }
        return;
    }
    const int cid = id - 771;                // 0..2047
    const int pt = cid & 63, ct = (cid >> 6) & 3, b = cid >> 8;
    const float* src = x + (((size_t)(b * 256 + ct * 64)) << 12) + pt * 64;
#pragma unroll
    for (int i = 0; i < 16; ++i) {
        int idx = i * 256 + t;
        int cl = idx >> 6, pl = idx & 63;
        tile[cl][pl] = src[((size_t)cl << 12) + pl];
    }
    __syncthreads();
#pragma unroll
    for (int i = 0; i < 8; ++i) {            // xb: [px][ch] transposed bf16
        int idx = i * 256 + t;
        int pl = idx >> 5, c2 = idx & 31;
        int cl = c2 * 2;
        u32 lo = f2bf(tile[cl][pl]);
        u32 hi = f2bf(tile[cl + 1][pl]);
        *(u32*)(xb + (((size_t)(b * 4096 + pt * 64 + pl)) << 9) + ct * 64 + cl) = lo | (hi << 16);
    }
#pragma unroll
    for (int i = 0; i < 8; ++i) {            // xc: [c][px] bf16 cast (same layout as x)
        int idx = i * 256 + t;
        int cl = idx >> 5, pl2 = (idx & 31) * 2;
        u32 lo = f2bf(tile[cl][pl2]);
        u32 hi = f2bf(tile[cl][pl2 + 1]);
        *(u32*)(xc + (((size_t)(b * 256 + ct * 64 + cl)) << 12) + pt * 64 + pl2) = lo | (hi << 16);
    }
    if (t < 64) {
        float s = 0.f;
#pragma unroll
        for (int i = 0; i < 64; ++i) s += tile[t][i];
        atomicAdd(&pool[(b << 9) + ct * 64 + t], s * (1.f / 4096.f));
    }
}

// ---------------- bf16 MFMA GEMM: out = relu(W @ X + bias) (single-buffer, R3 form) ----------------
template<int KIN, bool OUTT, bool DOPOOL>
__global__ __launch_bounds__(256) void k_gemm(
    const u16* __restrict__ xb, const u16* __restrict__ Wb,
    const float* __restrict__ biasf, void* __restrict__ outp,
    float* __restrict__ poolp)
{
    __shared__ __align__(16) u16 Wl[4096];
    __shared__ __align__(16) u16 Xl[4096];
    __shared__ __align__(16) u16 ct[OUTT ? 16384 : 4];
    __shared__ float sbias[128];
    const int t = threadIdx.x;
    const int lane = t & 63;
    const int wv = t >> 6;
    const int id = blockIdx.x;
    const int p_blk = (((id >> 4) << 3) | (id & 7)) * 128;
    const int o_blk = ((id >> 3) & 1) * 128;
    const int owg = (wv & 1) * 4;
    const int pwg = (wv >> 1) * 4;
    const int r16 = lane & 15, q = lane >> 4;
    if (t < 128) sbias[t] = biasf[o_blk + t];

    f32x4 acc[4][4];
#pragma unroll
    for (int i = 0; i < 4; ++i)
#pragma unroll
        for (int j = 0; j < 4; ++j) acc[i][j] = (f32x4){0.f, 0.f, 0.f, 0.f};

    for (int kc = 0; kc < KIN / 32; ++kc) {
        const int kk = kc * 32 + q * 8;
#pragma unroll
        for (int s = 0; s < 4; ++s) {
            const int bi = wv * 4 + s;
            const u16* g;
            u16* l;
            if (bi < 8) {
                g = Wb + (size_t)(o_blk + bi * 16 + r16) * KIN + kk;
                l = Wl + bi * 512;
            } else {
                g = xb + (((size_t)(p_blk + (bi - 8) * 16 + r16)) << 9) + kk;
                l = Xl + (bi - 8) * 512;
            }
            ld_g2l_16(l, g);
        }
        __syncthreads();
        short8 af[4], bf[4];
#pragma unroll
        for (int i = 0; i < 4; ++i) af[i] = *(const short8*)(Wl + (owg + i) * 512 + lane * 8);
#pragma unroll
        for (int j = 0; j < 4; ++j) bf[j] = *(const short8*)(Xl + (pwg + j) * 512 + lane * 8);
#pragma unroll
        for (int i = 0; i < 4; ++i)
#pragma unroll
            for (int j = 0; j < 4; ++j)
                acc[i][j] = __builtin_amdgcn_mfma_f32_16x16x32_bf16(af[i], bf[j], acc[i][j], 0, 0, 0);
        __syncthreads();
    }

    float bia[4][4];
#pragma unroll
    for (int i = 0; i < 4; ++i)
#pragma unroll
        for (int r = 0; r < 4; ++r) bia[i][r] = sbias[owg * 16 + i * 16 + q * 4 + r];
    const int bidx = p_blk >> 12;

    if (OUTT) {
        // transpose epilogue: acc -> ct[px][ch] (XOR-swizzled), then coalesced store
#pragma unroll
        for (int i = 0; i < 4; ++i) {
#pragma unroll
            for (int j = 0; j < 4; ++j) {
                const int px_l = pwg * 16 + j * 16 + r16;
#pragma unroll
                for (int rp = 0; rp < 2; ++rp) {
                    const int r0 = rp * 2;
                    const int o_l = owg * 16 + i * 16 + q * 4 + r0;
                    const float v0 = fmaxf(acc[i][j][r0] + bia[i][r0], 0.f);
                    const float v1 = fmaxf(acc[i][j][r0 + 1] + bia[i][r0 + 1], 0.f);
                    const u32 pk = (u32)f2bf(v0) | ((u32)f2bf(v1) << 16);
                    *(u32*)((char*)ct + px_l * 256 + ((o_l * 2) ^ ((px_l & 7) << 4))) = pk;
                }
            }
        }
        __syncthreads();
        u16* feT = (u16*)outp;
#pragma unroll
        for (int it = 0; it < 16; ++it) {
            const int idx = it * 256 + t;
            const int px_l = idx >> 5, cd = idx & 31;
            s16x4 v = *(const s16x4*)((char*)ct + px_l * 256 + ((cd * 8) ^ ((px_l & 7) << 4)));
            *(s16x4*)(feT + (((size_t)(bidx * 4096 + (p_blk & 4095) + px_l)) << 8) + o_blk + cd * 4) = v;
        }
        return;
    }

    const int pin0 = (p_blk & 4095) + pwg * 16 + r16;
#pragma unroll
    for (int i = 0; i < 4; ++i) {
#pragma unroll
        for (int r = 0; r < 4; ++r) {
            const int o = o_blk + owg * 16 + i * 16 + q * 4 + r;
            const size_t rowb = ((size_t)(bidx * 256 + o)) << 12;
            float ps = 0.f;
#pragma unroll
            for (int j = 0; j < 4; ++j) {
                float v = fmaxf(acc[i][j][r] + bia[i][r], 0.f);
                const size_t oi = rowb + pin0 + j * 16;
                ((u16*)outp)[oi] = f2bf(v);
                ps += v;
            }
            if (DOPOOL) {
                ps += __shfl_down(ps, 8, 16);
                ps += __shfl_down(ps, 4, 16);
                ps += __shfl_down(ps, 2, 16);
                ps += __shfl_down(ps, 1, 16);
                if (r16 == 0)
                    atomicAdd(&poolp[(bidx << 9) + 256 + o], ps * (1.f / 4096.f));
            }
        }
    }
}

// ---------------- fused sim + softmax + aggregation (NO LDS STAGING) ----------------
// Dot phase remapped for perfect coalescing: thread = (px = t>>3, c8 = t&7); each
// thread owns a STRIDED channel set {c8, c8+8, c8+16, c8+24}-th 16B chunks (dot
// products are permutation-invariant over channels). Per load instruction, lanes
// 0-7 read one contiguous 128B line -> 8 fully-consumed lines/instr (was 64).
__global__ __launch_bounds__(512) void k_simagg(
    const u16* __restrict__ fe, const u16* __restrict__ xb, u16* __restrict__ xbo)
{
    __shared__ float red[8][65][13];   // [c8][px(+pad)][9 dots + nn0 + nn2]
    __shared__ float ws9[9][64];
    const int t = threadIdx.x;
    const int id = blockIdx.x;
    const int b = id & 7, h = id >> 3;
    const int rows[3] = {h > 0 ? h - 1 : 0, h, h < 63 ? h + 1 : 63};

    // ---- dot phase (coalesced)
    {
        const int px = t >> 3, c8 = t & 7;
        const int pxl = px > 0 ? px - 1 : 0, pxr = px < 63 ? px + 1 : 63;
        const int pxs[3] = {pxl, px, pxr};
        const u16* feb = fe + (((size_t)(b * 4096)) << 8) + c8 * 8;
        float cvec[32];
        float dot[9];
        float nn0 = 0.f, nn2 = 0.f;
        {   // center (r=1, j=1)
            const u16* p = feb + (((size_t)(rows[1] * 64 + px)) << 8);
            float s = 0.f;
#pragma unroll
            for (int i = 0; i < 4; ++i) {
                short8 v = *(const short8*)(p + i * 64);
#pragma unroll
                for (int u = 0; u < 8; ++u) {
                    float f = bf2f((u16)v[u]);
                    cvec[i * 8 + u] = f;
                    s = fmaf(f, f, s);
                }
            }
            dot[4] = s;
        }
#pragma unroll
        for (int r = 0; r < 3; ++r) {
#pragma unroll
            for (int j = 0; j < 3; ++j) {
                if (r == 1 && j == 1) continue;
                const int k = r * 3 + j;
                const u16* p = feb + (((size_t)(rows[r] * 64 + pxs[j])) << 8);
                float s = 0.f, qq = 0.f;
#pragma unroll
                for (int i = 0; i < 4; ++i) {
                    short8 v = *(const short8*)(p + i * 64);
#pragma unroll
                    for (int u = 0; u < 8; ++u) {
                        float f = bf2f((u16)v[u]);
                        s = fmaf(cvec[i * 8 + u], f, s);
                        if (j == 1) qq = fmaf(f, f, qq);
                    }
                }
                dot[k] = s;
                if (j == 1) { if (r == 0) nn0 = qq; else nn2 = qq; }
            }
        }
#pragma unroll
        for (int k = 0; k < 9; ++k) red[c8][px][k] = dot[k];
        red[c8][px][9] = nn0;
        red[c8][px][10] = nn2;
    }
    __syncthreads();
    // ---- softmax on wave 0 (w = pixel)
    if (t < 64) {
        const int w = t;
        float dk[9];
#pragma unroll
        for (int k = 0; k < 9; ++k) {
            float s = red[0][w][k];
#pragma unroll
            for (int g = 1; g < 8; ++g) s += red[g][w][k];
            dk[k] = s;
        }
        float nr0 = red[0][w][9], nr2 = red[0][w][10];
#pragma unroll
        for (int g = 1; g < 8; ++g) { nr0 += red[g][w][9]; nr2 += red[g][w][10]; }
        float nr[3] = {nr0, dk[4], nr2};
        const float nc = sqrtf(dk[4]);
        float sv[9], mk[9];
#pragma unroll
        for (int di = -1; di <= 1; ++di) {
#pragma unroll
            for (int dj = -1; dj <= 1; ++dj) {
                const int k = (di + 1) * 3 + (dj + 1);
                const int hn = h + di, wn = w + dj;
                const float mask = (hn >= 0 && hn < 64 && wn >= 0 && wn < 64) ? 1.f : 0.f;
                const int wc = wn < 0 ? 0 : (wn > 63 ? 63 : wn);
                const float nk = __shfl(nr[di + 1], wc, 64);
                mk[k] = mask;
                sv[k] = mask * dk[k] / (nc * sqrtf(nk) + 1e-7f);
            }
        }
        float mx = sv[0];
#pragma unroll
        for (int k = 1; k < 9; ++k) mx = fmaxf(mx, sv[k]);
        float e[9], sum = 0.f;
#pragma unroll
        for (int k = 0; k < 9; ++k) { e[k] = expf(sv[k] - mx); sum += e[k]; }
        const float rs = 1.f / sum;
#pragma unroll
        for (int k = 0; k < 9; ++k) ws9[k][w] = mk[k] * e[k] * rs;
    }
    __syncthreads();
    // ---- aggregation: 9 independent loads per px (coalesced rows)
    const int cd = t & 63, pxg = t >> 6;
    const u16* xbb = xb + (((size_t)(b * 4096)) << 9) + cd * 4;
    u16* orow = xbo + (((size_t)(b * 4096 + h * 64)) << 9) + 256 + cd * 4;
#pragma unroll
    for (int pi = 0; pi < 8; ++pi) {
        const int px = pxg * 8 + pi;
        const int pL = px > 0 ? px - 1 : 0, pR = px < 63 ? px + 1 : 63;
        const int pxs2[3] = {pL, px, pR};
        float m9[9];
#pragma unroll
        for (int k = 0; k < 9; ++k) m9[k] = ws9[k][px];
        float a0 = 0.f, a1 = 0.f, a2 = 0.f, a3 = 0.f;
#pragma unroll
        for (int r = 0; r < 3; ++r) {
#pragma unroll
            for (int j = 0; j < 3; ++j) {
                const float m = m9[r * 3 + j];
                s16x4 v = *(const s16x4*)(xbb + (((size_t)(rows[r] * 64 + pxs2[j])) << 9));
                a0 = fmaf(bf2f((u16)v[0]), m, a0);
                a1 = fmaf(bf2f((u16)v[1]), m, a1);
                a2 = fmaf(bf2f((u16)v[2]), m, a2);
                a3 = fmaf(bf2f((u16)v[3]), m, a3);
            }
        }
        s16x4 sv4;
        sv4[0] = (short)f2bf(a0); sv4[1] = (short)f2bf(a1);
        sv4[2] = (short)f2bf(a2); sv4[3] = (short)f2bf(a3);
        *(s16x4*)(orow + ((size_t)px << 9)) = sv4;
    }
}

// ---------------- final: gate MLP (per-block recompute) + residual add ----------------
__global__ __launch_bounds__(256) void k_final(
    const u16* __restrict__ xc, const u16* __restrict__ enh,
    const float* __restrict__ pool,
    const float* __restrict__ wg1, const float* __restrict__ bg1,
    const float* __restrict__ wg2, const float* __restrict__ bg2,
    float* __restrict__ out)
{
    __shared__ float pl[512];
    __shared__ float hpart[4][64];
    __shared__ float hb[64];
    __shared__ float sg[256];
    const int t = threadIdx.x;
    const int id = blockIdx.x;               // 512 = b(8) x 64 ch-groups
    const int b = id & 7, cg = id >> 3;
    pl[t] = pool[b * 512 + t];
    pl[t + 256] = pool[b * 512 + 256 + t];
    __syncthreads();
    {
        const int o = t & 63, seg = t >> 6;
        float s = 0.f;
        const float* wr_ = wg1 + o * 512 + seg * 128;
        const float* pr_ = pl + seg * 128;
#pragma unroll 4
        for (int j = 0; j < 128; ++j) s = fmaf(wr_[j], pr_[j], s);
        hpart[seg][o] = s;
    }
    __syncthreads();
    if (t < 64)
        hb[t] = fmaxf(hpart[0][t] + hpart[1][t] + hpart[2][t] + hpart[3][t] + bg1[t], 0.f);
    __syncthreads();
    {
        float s2 = bg2[t];
        const float* w2 = wg2 + t * 64;
#pragma unroll 4
        for (int j = 0; j < 64; ++j) s2 = fmaf(w2[j], hb[j], s2);
        sg[t] = 1.f / (1.f + expf(-s2));
    }
    __syncthreads();
    const int cl = t >> 6, l = t & 63;
    const int c = cg * 4 + cl;
    const float gt = sg[c];
    const u16* xp = xc + (((size_t)(b * 256 + c)) << 12);
    const u16* ep = enh + (((size_t)(b * 256 + c)) << 12);
    float*     op = out + (((size_t)(b * 256 + c)) << 12);
#pragma unroll
    for (int ch = 0; ch < 8; ++ch) {         // 8 chunks of 512 px
        const int base = ch * 512 + l * 8;
        short8 ev = *(const short8*)(ep + base);
        short8 xv = *(const short8*)(xp + base);
        float4 o0, o1;
        o0.x = fmaf(gt, bf2f((u16)ev[0]), bf2f((u16)xv[0]));
        o0.y = fmaf(gt, bf2f((u16)ev[1]), bf2f((u16)xv[1]));
        o0.z = fmaf(gt, bf2f((u16)ev[2]), bf2f((u16)xv[2]));
        o0.w = fmaf(gt, bf2f((u16)ev[3]), bf2f((u16)xv[3]));
        o1.x = fmaf(gt, bf2f((u16)ev[4]), bf2f((u16)xv[4]));
        o1.y = fmaf(gt, bf2f((u16)ev[5]), bf2f((u16)xv[5]));
        o1.z = fmaf(gt, bf2f((u16)ev[6]), bf2f((u16)xv[6]));
        o1.w = fmaf(gt, bf2f((u16)ev[7]), bf2f((u16)xv[7]));
        *(float4*)(op + base) = o0;
        *(float4*)(op + base + 4) = o1;
    }
}

extern "C" void kernel_launch(void* const* d_in, const int* in_sizes, int n_in,
                              void* d_out, int out_size, void* d_ws, size_t ws_size,
                              hipStream_t stream)
{
    const float* x       = (const float*)d_in[0];
    const float* w_embed = (const float*)d_in[1];
    const float* b_embed = (const float*)d_in[2];
    const float* g1      = (const float*)d_in[3];
    const float* be1     = (const float*)d_in[4];
    const float* m1      = (const float*)d_in[5];
    const float* v1      = (const float*)d_in[6];
    const float* w_enh   = (const float*)d_in[7];
    const float* b_enh   = (const float*)d_in[8];
    const float* g2      = (const float*)d_in[9];
    const float* be2     = (const float*)d_in[10];
    const float* m2      = (const float*)d_in[11];
    const float* v2      = (const float*)d_in[12];
    const float* w_g1    = (const float*)d_in[13];
    const float* b_g1    = (const float*)d_in[14];
    const float* w_g2    = (const float*)d_in[15];
    const float* b_g2    = (const float*)d_in[16];
    float* ws  = (float*)d_ws;
    float* out = (float*)d_out;

    u16*   xb   = (u16*)(ws + OFS_XB);
    u16*   w1b  = (u16*)(ws + OFS_W1B);
    u16*   w2b  = (u16*)(ws + OFS_W2B);
    float* b1f  = ws + OFS_B1;
    float* b2f  = ws + OFS_B2;
    float* pool = ws + OFS_POOL;
    u16*   enh  = (u16*)(ws + OFS_ENH);
    u16*   xc   = (u16*)(ws + OFS_XC);
    u16*   fe   = (u16*)d_out;   // fe (bf16 [b][px][ch]) in d_out; dead before k_final writes

    k_cvt<<<dim3(2819), dim3(256), 0, stream>>>(
        x, xb, xc, pool,
        w_embed, b_embed, g1, be1, m1, v1,
        w_enh, b_enh, g2, be2, m2, v2, w1b, w2b, b1f, b2f);
    k_gemm<256, true, false><<<dim3(512), dim3(256), 0, stream>>>(xb, w1b, b1f, (void*)fe, nullptr);
    k_simagg<<<dim3(512), dim3(512), 0, stream>>>(fe, xb, xb);
    k_gemm<512, false, true><<<dim3(512), dim3(256), 0, stream>>>(xb, w2b, b2f, (void*)enh, pool);
    k_final<<<dim3(512), dim3(256), 0, stream>>>(xc, enh, pool, w_g1, b_g1, w_g2, b_g2, out);
}